// Round 5
// baseline (162.196 us; speedup 1.0000x reference)
//
#include <hip/hip_runtime.h>

#define IN_F    4096
#define OUT_F   4096
#define K_DIM   4096
#define NNZ_C   838860
#define BATCH   512
#define BK      32
#define BM      128
#define BN      128

typedef short bf16x8 __attribute__((ext_vector_type(8)));
typedef float f32x4  __attribute__((ext_vector_type(4)));

__device__ __forceinline__ unsigned short f2bf(float f) {  // RNE fp32->bf16
    unsigned u = __float_as_uint(f);
    u += 0x7fffu + ((u >> 16) & 1u);
    return (unsigned short)(u >> 16);
}
__device__ __forceinline__ void gload_lds16(const void* g, void* l) {
    __builtin_amdgcn_global_load_lds(
        (const __attribute__((address_space(1))) unsigned int*)g,
        (__attribute__((address_space(3))) unsigned int*)l, 16, 0, 0);
}

// ---------------------------------------------------------------------------
// K1 "zero_w": zero the dense W buffer (must fully precede the scatter).
// 33.5 MB write-only ~= 7 us.
// ---------------------------------------------------------------------------
#define N_WZ   (OUT_F * K_DIM / 8)       // 2097152 uint4 stores
__global__ void zero_w(uint4* __restrict__ Wz) {
    int i = blockIdx.x * 256 + threadIdx.x;
    Wz[i] = make_uint4(0, 0, 0, 0);
}
#define ZW_BLOCKS (N_WZ / 256)           // 8192

// ---------------------------------------------------------------------------
// K2 "scatcvt": COO scatter-add (fire-and-forget packed-bf16 atomics, exact
// duplicate handling) + x fp32->bf16 conversion in the SAME dispatch.
// R9/R10 established: scatter is atomic-pipe-bound (~19 G atomic/s,
// occupancy-invariant); the cvt's 13 MB rides along ~free (dur 44 -> 46-48
// while absorbing the whole cvt). Fallback path also seeds out=bias here.
// ---------------------------------------------------------------------------
#define N_CVT   (BATCH * K_DIM / 8)      // 262144 bf16x8 outputs
#define N_OUT   (BATCH * OUT_F / 4)      // 524288 float4 stores (fallback)
#define NS_BLK  ((NNZ_C / 4 + 255) / 256)   // 820 scatter blocks
#define NC_BLK  (N_CVT / 256)               // 1024 cvt blocks
#define NB_BLK  (N_OUT / 256)               // 2048 bias blocks (fallback only)
__global__ void scatcvt(const int* __restrict__ row_idx,
                        const int* __restrict__ col_idx,
                        const float* __restrict__ values,
                        unsigned short* __restrict__ W,
                        const float* __restrict__ x,
                        unsigned short* __restrict__ xb,
                        const float* __restrict__ bias,
                        float* __restrict__ out) {
    int b = blockIdx.x;
    if (b < NS_BLK) {
        int i = b * 256 + threadIdx.x;           // NNZ_C/4 = 209715 entries
        if (i >= NNZ_C / 4) return;
        int4   r4 = ((const int4*)row_idx)[i];
        int4   c4 = ((const int4*)col_idx)[i];
        float4 v4 = ((const float4*)values)[i];
#pragma unroll
        for (int j = 0; j < 4; ++j) {
            int r = (&r4.x)[j], c = (&c4.x)[j];
            float v = (&v4.x)[j];
            unsigned idx = (unsigned)r * K_DIM + (unsigned)c;
            unsigned short h = f2bf(v);
            unsigned data = (idx & 1u) ? ((unsigned)h << 16) : (unsigned)h;
            unsigned long long addr = (unsigned long long)(W + (idx & ~1u));
            asm volatile("global_atomic_pk_add_bf16 %0, %1, off"
                         :: "v"(addr), "v"(data) : "memory");
        }
        return;
    }
    b -= NS_BLK;
    if (b < NC_BLK) {
        int i = b * 256 + threadIdx.x;
        const float4* p = (const float4*)x + (size_t)i * 2;
        float4 a = p[0], bb = p[1];
        union { unsigned short h[8]; bf16x8 v; } u;
        u.h[0] = f2bf(a.x);  u.h[1] = f2bf(a.y);  u.h[2] = f2bf(a.z);  u.h[3] = f2bf(a.w);
        u.h[4] = f2bf(bb.x); u.h[5] = f2bf(bb.y); u.h[6] = f2bf(bb.z); u.h[7] = f2bf(bb.w);
        ((bf16x8*)xb)[i] = u.v;
        return;
    }
    b -= NC_BLK;                                  // fallback-only bias seed
    int i = b * 256 + threadIdx.x;
    if (i < N_OUT) {
        float4 bb = ((const float4*)bias)[i & (OUT_F / 4 - 1)];
        ((float4*)out)[i] = bb;
    }
}

// ---------------------------------------------------------------------------
// K3: bf16 GEMM, B^T layout, 128x128 tile, verified conflict-free XOR
// swizzle VERBATIM (both staging pre-swizzle and read swizzle -- rule 21).
// R11: R10's counted-vmcnt depth-2 plane pipeline (sync skeleton passed
// correctness in R10) WITHOUT the context-poisoned hints:
//   - NO s_setprio in a lockstep loop (m190: measured-negative there)
//   - NO sched_barrier(0) pinning (m141: defeats compiler scheduling)
// Last iteration peeled so the main loop is branch-free on the vmcnt arg.
// Per main plane-step: {vmcnt(4); s_barrier; ds_read x8; lgkmcnt(0);
//                       s_barrier; stage(k+2); 16 MFMA}
// Template: SK = split-K; EPI 0 = plain-store (s==0 -> out+bias, s>0 ->
// parts[s-1]); EPI 1 = atomicAdd fallback. SK=8 -> 1024 blocks = 4/CU.
// ---------------------------------------------------------------------------
template <int EPI, int SK>
__global__ void __launch_bounds__(256)
gemm_bt(const unsigned short* __restrict__ Abf,   // [512][4096] bf16
        const unsigned short* __restrict__ Wbf,   // [4096][4096] bf16
        const float* __restrict__ bias,
        float* __restrict__ out,                  // [512][4096] f32
        float* __restrict__ parts) {              // (SK-1) x [512][4096] f32
    __shared__ __align__(16) unsigned short As[2][BM * BK];   // 2 planes x 8 KB
    __shared__ __align__(16) unsigned short Bs[2][BN * BK];   // 2 planes x 8 KB

    const int nt = blockIdx.x, mt = blockIdx.y, s = blockIdx.z;
    const int t = threadIdx.x, w = t >> 6, ln = t & 63;
    const int wm = w & 1, wn = w >> 1;
    const int KSs = K_DIM / SK;
    const int ks0 = s * KSs;

    // staging: lane ln -> LDS row (ln>>2), physical chunk (ln&3);
    // global source = logical chunk (ln&3) ^ ((ln>>3)&3)   [measured: 0 conflicts]
    const int srow = w * 16 + (ln >> 2);
    const int scol = (((ln & 3) ^ ((ln >> 3) & 3)) * 8);
    const unsigned short* gA0 = Abf + (size_t)(mt * BM + srow) * K_DIM + ks0 + scol;
    const unsigned short* gA1 = gA0 + (size_t)64 * K_DIM;
    const unsigned short* gB0 = Wbf + (size_t)(nt * BN + srow) * K_DIM + ks0 + scol;
    const unsigned short* gB1 = gB0 + (size_t)64 * K_DIM;
    const int lA0o = (w * 16) * BK;          // LDS dest offsets (wave-uniform)
    const int lA1o = (64 + w * 16) * BK;

    // read: logical quad q -> physical chunk q ^ ((lanem>>1)&3)
    const int quad = ln >> 4, lanem = ln & 15;
    const int rsw = (quad ^ ((lanem >> 1) & 3)) * 8;
    const int rAo = (wm * 64 + lanem) * BK + rsw;
    const int rBo = (wn * 64 + lanem) * BK + rsw;

    f32x4 acc[4][4];
#pragma unroll
    for (int mi = 0; mi < 4; ++mi)
#pragma unroll
        for (int ni = 0; ni < 4; ++ni)
            acc[mi][ni] = (f32x4){0.f, 0.f, 0.f, 0.f};

    // stage one 32-wide plane: 4 global_load_lds x16B per wave
    auto stageP = [&](int p, int kp) {
        const int off = kp * BK;
        gload_lds16(gA0 + off, &As[p][lA0o]);
        gload_lds16(gA1 + off, &As[p][lA1o]);
        gload_lds16(gB0 + off, &Bs[p][lA0o]);
        gload_lds16(gB1 + off, &Bs[p][lA1o]);
    };

    auto planeMFMA = [&](int p) {
        const unsigned short* rA = &As[p][0] + rAo;
        const unsigned short* rB = &Bs[p][0] + rBo;
        bf16x8 af[4], bfr[4];
#pragma unroll
        for (int mi = 0; mi < 4; ++mi) af[mi]  = *(const bf16x8*)(rA + mi * 16 * BK);
#pragma unroll
        for (int ni = 0; ni < 4; ++ni) bfr[ni] = *(const bf16x8*)(rB + ni * 16 * BK);
        // my reads done -> after next barrier this plane is free to refill.
        asm volatile("s_waitcnt lgkmcnt(0)" ::: "memory");
        asm volatile("s_barrier" ::: "memory");
#pragma unroll
        for (int mi = 0; mi < 4; ++mi)
#pragma unroll
            for (int ni = 0; ni < 4; ++ni)
                acc[mi][ni] = __builtin_amdgcn_mfma_f32_16x16x32_bf16(
                    af[mi], bfr[ni], acc[mi][ni], 0, 0, 0);
    };

    const int NKP = KSs / BK;                // 16 at SK=8, 32 at SK=4
    stageP(0, 0);                            // 4 VMEM in flight
    stageP(1, 1);                            // 8 VMEM in flight

#pragma unroll 2
    for (int k = 0; k < NKP - 1; ++k) {      // main: branch-free vmcnt(4)
        const int p = k & 1;
        // my plane-k loads complete; plane k+1's 4 stay in flight
        asm volatile("s_waitcnt vmcnt(4)" ::: "memory");
        asm volatile("s_barrier" ::: "memory");   // ALL waves' plane-k ready
        // (inside planeMFMA: ds_read; lgkmcnt(0); s_barrier -> plane free)
        // refill is issued between the free-barrier and the MFMAs of the
        // NEXT loop body by the scheduler; semantically it sits here:
        const unsigned short* rA = &As[p][0] + rAo;
        const unsigned short* rB = &Bs[p][0] + rBo;
        bf16x8 af[4], bfr[4];
#pragma unroll
        for (int mi = 0; mi < 4; ++mi) af[mi]  = *(const bf16x8*)(rA + mi * 16 * BK);
#pragma unroll
        for (int ni = 0; ni < 4; ++ni) bfr[ni] = *(const bf16x8*)(rB + ni * 16 * BK);
        asm volatile("s_waitcnt lgkmcnt(0)" ::: "memory");  // my reads executed
        asm volatile("s_barrier" ::: "memory");   // plane p now FREE
        if (k + 2 < NKP) stageP(p, k + 2);        // refill; flies under MFMAs
#pragma unroll
        for (int mi = 0; mi < 4; ++mi)
#pragma unroll
            for (int ni = 0; ni < 4; ++ni)
                acc[mi][ni] = __builtin_amdgcn_mfma_f32_16x16x32_bf16(
                    af[mi], bfr[ni], acc[mi][ni], 0, 0, 0);
    }
    {   // peeled last plane: only its own 4 loads outstanding
        const int p = (NKP - 1) & 1;
        asm volatile("s_waitcnt vmcnt(0)" ::: "memory");
        asm volatile("s_barrier" ::: "memory");
        const unsigned short* rA = &As[p][0] + rAo;
        const unsigned short* rB = &Bs[p][0] + rBo;
        bf16x8 af[4], bfr[4];
#pragma unroll
        for (int mi = 0; mi < 4; ++mi) af[mi]  = *(const bf16x8*)(rA + mi * 16 * BK);
#pragma unroll
        for (int ni = 0; ni < 4; ++ni) bfr[ni] = *(const bf16x8*)(rB + ni * 16 * BK);
#pragma unroll
        for (int mi = 0; mi < 4; ++mi)
#pragma unroll
            for (int ni = 0; ni < 4; ++ni)
                acc[mi][ni] = __builtin_amdgcn_mfma_f32_16x16x32_bf16(
                    af[mi], bfr[ni], acc[mi][ni], 0, 0, 0);
    }

    // C/D layout: col = lanem, row = quad*4 + r; 16 lanes = one 64B segment.
    const int row0 = mt * BM + wm * 64 + quad * 4;
    const int col0 = nt * BN + wn * 64 + lanem;
    if (EPI == 0) {
        float bv[4];
#pragma unroll
        for (int ni = 0; ni < 4; ++ni) bv[ni] = (s == 0) ? bias[col0 + ni * 16] : 0.f;
        float* dst = (s == 0) ? out : parts + (size_t)(s - 1) * BATCH * OUT_F;
#pragma unroll
        for (int mi = 0; mi < 4; ++mi)
#pragma unroll
            for (int ni = 0; ni < 4; ++ni)
#pragma unroll
                for (int r = 0; r < 4; ++r)
                    dst[(size_t)(row0 + mi * 16 + r) * OUT_F + col0 + ni * 16] =
                        acc[mi][ni][r] + bv[ni];
    } else {
#pragma unroll
        for (int mi = 0; mi < 4; ++mi)
#pragma unroll
            for (int ni = 0; ni < 4; ++ni)
#pragma unroll
                for (int r = 0; r < 4; ++r)
                    atomicAdd(&out[(size_t)(row0 + mi * 16 + r) * OUT_F + col0 + ni * 16],
                              acc[mi][ni][r]);
    }
}

// ---------------------------------------------------------------------------
// K4: out += sum(parts[0..6])  (75 MB streamed, ~12 us). Separate kernel:
// the kernel boundary is ONE cheap system-scope flush -- R8 showed per-block
// device fences (buffer_wbl2 x1024) cost ~150 us. Do not re-fuse.
// ---------------------------------------------------------------------------
__global__ void reduce_parts(float* __restrict__ out,
                             const float* __restrict__ parts) {
    int i = blockIdx.x * 256 + threadIdx.x;          // 524288 float4s
    float4 a = ((const float4*)out)[i];
#pragma unroll
    for (int p = 0; p < 7; ++p) {
        float4 b = ((const float4*)(parts + (size_t)p * BATCH * OUT_F))[i];
        a.x += b.x; a.y += b.y; a.z += b.z; a.w += b.w;
    }
    ((float4*)out)[i] = a;
}

// ---------------------------------------------------------------------------
// ws: xb 4.19 | W 33.55 | parts 7 x 8.39 = 58.72  -> 96.5 MB (fallback if less)
// ---------------------------------------------------------------------------
extern "C" void kernel_launch(void* const* d_in, const int* in_sizes, int n_in,
                              void* d_out, int out_size, void* d_ws, size_t ws_size,
                              hipStream_t stream) {
    const float* x       = (const float*)d_in[0];
    const int*   row_idx = (const int*)d_in[1];
    const int*   col_idx = (const int*)d_in[2];
    const float* values  = (const float*)d_in[3];
    const float* bias    = (const float*)d_in[4];
    float*       out     = (float*)d_out;

    unsigned short* xb = (unsigned short*)d_ws;
    unsigned short* W  = xb + (size_t)BATCH * K_DIM;
    float* parts = (float*)(W + (size_t)OUT_F * K_DIM);
    size_t need = (size_t)BATCH * K_DIM * 2 + (size_t)OUT_F * K_DIM * 2
                + (size_t)7 * BATCH * OUT_F * 4;
    bool use_parts = (ws_size >= need);

    zero_w<<<ZW_BLOCKS, 256, 0, stream>>>((uint4*)W);

    int sc_blocks = NS_BLK + NC_BLK + (use_parts ? 0 : NB_BLK);
    scatcvt<<<sc_blocks, 256, 0, stream>>>(row_idx, col_idx, values, W,
                                           x, xb, bias, out);

    if (use_parts) {
        gemm_bt<0, 8><<<dim3(OUT_F / BN, BATCH / BM, 8), 256, 0, stream>>>(
            xb, W, bias, out, parts);
        reduce_parts<<<BATCH * OUT_F / 4 / 256, 256, 0, stream>>>(out, parts);
    } else {
        gemm_bt<1, 4><<<dim3(OUT_F / BN, BATCH / BM, 4), 256, 0, stream>>>(
            xb, W, bias, out, nullptr);
    }
}

// Round 6
// 147.034 us; speedup vs baseline: 1.1031x; 1.1031x over previous
//
#include <hip/hip_runtime.h>

#define IN_F    4096
#define OUT_F   4096
#define K_DIM   4096
#define NNZ_C   838860
#define BATCH   512
#define BK      32
#define BM      128
#define BN      128

typedef short bf16x8 __attribute__((ext_vector_type(8)));
typedef float f32x4  __attribute__((ext_vector_type(4)));

__device__ __forceinline__ unsigned short f2bf(float f) {  // RNE fp32->bf16
    unsigned u = __float_as_uint(f);
    u += 0x7fffu + ((u >> 16) & 1u);
    return (unsigned short)(u >> 16);
}
__device__ __forceinline__ void gload_lds16(const void* g, void* l) {
    __builtin_amdgcn_global_load_lds(
        (const __attribute__((address_space(1))) unsigned int*)g,
        (__attribute__((address_space(3))) unsigned int*)l, 16, 0, 0);
}

// ---------------------------------------------------------------------------
// K1 "zero_w": zero the dense W buffer (must fully precede the scatter).
// 33.5 MB write-only ~= 7 us.
// ---------------------------------------------------------------------------
#define N_WZ   (OUT_F * K_DIM / 8)       // 2097152 uint4 stores
__global__ void zero_w(uint4* __restrict__ Wz) {
    int i = blockIdx.x * 256 + threadIdx.x;
    Wz[i] = make_uint4(0, 0, 0, 0);
}
#define ZW_BLOCKS (N_WZ / 256)           // 8192

// ---------------------------------------------------------------------------
// K2 "scatcvt": COO scatter-add (fire-and-forget packed-bf16 atomics, exact
// duplicate handling) + x fp32->bf16 conversion in the SAME dispatch.
// R9/R10: scatter is atomic-pipe-bound (~19 G atomic/s, occupancy-invariant);
// the cvt's 13 MB rides along ~free. Fallback path also seeds out=bias.
// ---------------------------------------------------------------------------
#define N_CVT   (BATCH * K_DIM / 8)      // 262144 bf16x8 outputs
#define N_OUT   (BATCH * OUT_F / 4)      // 524288 float4 stores (fallback)
#define NS_BLK  ((NNZ_C / 4 + 255) / 256)   // 820 scatter blocks
#define NC_BLK  (N_CVT / 256)               // 1024 cvt blocks
#define NB_BLK  (N_OUT / 256)               // 2048 bias blocks (fallback only)
__global__ void scatcvt(const int* __restrict__ row_idx,
                        const int* __restrict__ col_idx,
                        const float* __restrict__ values,
                        unsigned short* __restrict__ W,
                        const float* __restrict__ x,
                        unsigned short* __restrict__ xb,
                        const float* __restrict__ bias,
                        float* __restrict__ out) {
    int b = blockIdx.x;
    if (b < NS_BLK) {
        int i = b * 256 + threadIdx.x;           // NNZ_C/4 = 209715 entries
        if (i >= NNZ_C / 4) return;
        int4   r4 = ((const int4*)row_idx)[i];
        int4   c4 = ((const int4*)col_idx)[i];
        float4 v4 = ((const float4*)values)[i];
#pragma unroll
        for (int j = 0; j < 4; ++j) {
            int r = (&r4.x)[j], c = (&c4.x)[j];
            float v = (&v4.x)[j];
            unsigned idx = (unsigned)r * K_DIM + (unsigned)c;
            unsigned short h = f2bf(v);
            unsigned data = (idx & 1u) ? ((unsigned)h << 16) : (unsigned)h;
            unsigned long long addr = (unsigned long long)(W + (idx & ~1u));
            asm volatile("global_atomic_pk_add_bf16 %0, %1, off"
                         :: "v"(addr), "v"(data) : "memory");
        }
        return;
    }
    b -= NS_BLK;
    if (b < NC_BLK) {
        int i = b * 256 + threadIdx.x;
        const float4* p = (const float4*)x + (size_t)i * 2;
        float4 a = p[0], bb = p[1];
        union { unsigned short h[8]; bf16x8 v; } u;
        u.h[0] = f2bf(a.x);  u.h[1] = f2bf(a.y);  u.h[2] = f2bf(a.z);  u.h[3] = f2bf(a.w);
        u.h[4] = f2bf(bb.x); u.h[5] = f2bf(bb.y); u.h[6] = f2bf(bb.z); u.h[7] = f2bf(bb.w);
        ((bf16x8*)xb)[i] = u.v;
        return;
    }
    b -= NC_BLK;                                  // fallback-only bias seed
    int i = b * 256 + threadIdx.x;
    if (i < N_OUT) {
        float4 bb = ((const float4*)bias)[i & (OUT_F / 4 - 1)];
        ((float4*)out)[i] = bb;
    }
}

// ---------------------------------------------------------------------------
// K3: bf16 GEMM, B^T layout, 128x128 tile. R12: SK=4 with 512-thread 8-wave
// blocks -- 512 blocks = 2/CU x 8 waves = SAME 16 waves/CU as R9's
// 1024x256t, but parts traffic halves (7 -> 3 parts: gemm writes 67 -> 34 MB,
// reduce streams 75 -> 42 MB). R6's "2/CU barrier-stall" was 256-thread
// blocks (8 waves/CU); wave count here is unchanged. K-loop is R9's verbatim
// two-plane BK=64 __syncthreads structure (best measured: 158.2; counted-
// vmcnt R10/R11 measured null at this tile shape -- do not re-add).
// Per-wave tile 64x32 (acc 4x2). XOR staging/read swizzle preserved verbatim
// per 16-row group: each of 8 waves stages 16 rows of A + 16 of B per plane
// (same per-wave lane pattern); read rsw depends only on (quad,lanem).
// Template: SK = split-K; EPI 0 = plain-store (s==0 -> out+bias, s>0 ->
// parts[s-1]); EPI 1 = atomicAdd fallback.
// ---------------------------------------------------------------------------
template <int EPI, int SK>
__global__ void __launch_bounds__(512)
gemm_bt(const unsigned short* __restrict__ Abf,   // [512][4096] bf16
        const unsigned short* __restrict__ Wbf,   // [4096][4096] bf16
        const float* __restrict__ bias,
        float* __restrict__ out,                  // [512][4096] f32
        float* __restrict__ parts) {              // (SK-1) x [512][4096] f32
    __shared__ __align__(16) unsigned short As[2][BM * BK];   // 2 planes x 8 KB
    __shared__ __align__(16) unsigned short Bs[2][BN * BK];   // 2 planes x 8 KB

    const int nt = blockIdx.x, mt = blockIdx.y, s = blockIdx.z;
    const int t = threadIdx.x, w = t >> 6, ln = t & 63;   // w = 0..7
    const int wm = w & 1, wn = w >> 1;                    // 2 x 4 wave grid
    const int KSs = K_DIM / SK;                           // 1024 at SK=4
    const int ks0 = s * KSs;

    // staging: lane ln -> LDS row (ln>>2), physical chunk (ln&3);
    // global source = logical chunk (ln&3) ^ ((ln>>3)&3)   [measured: 0 conflicts]
    // wave w stages rows [w*16, w*16+16) of A and of B (8 waves cover 128).
    const int srow = w * 16 + (ln >> 2);
    const int scol = (((ln & 3) ^ ((ln >> 3) & 3)) * 8);
    const unsigned short* gA0 = Abf + (size_t)(mt * BM + srow) * K_DIM + ks0 + scol;
    const unsigned short* gB0 = Wbf + (size_t)(nt * BN + srow) * K_DIM + ks0 + scol;
    const int lA0o = (w * 16) * BK;          // LDS dest offset (wave-uniform)

    // read: logical quad q -> physical chunk q ^ ((lanem>>1)&3)
    const int quad = ln >> 4, lanem = ln & 15;
    const int rsw = (quad ^ ((lanem >> 1) & 3)) * 8;
    const int rAo = (wm * 64 + lanem) * BK + rsw;    // 64-row half
    const int rBo = (wn * 32 + lanem) * BK + rsw;    // 32-col quarter

    f32x4 acc[4][2];
#pragma unroll
    for (int mi = 0; mi < 4; ++mi)
#pragma unroll
        for (int ni = 0; ni < 2; ++ni)
            acc[mi][ni] = (f32x4){0.f, 0.f, 0.f, 0.f};

    // stage one 64-wide K-tile = two BK=32 planes (4 x global_load_lds x16B)
    auto stage = [&](int kt) {
#pragma unroll
        for (int ks = 0; ks < 2; ++ks) {
            const int off = kt * 64 + ks * BK;
            gload_lds16(gA0 + off, &As[ks][lA0o]);
            gload_lds16(gB0 + off, &Bs[ks][lA0o]);
        }
    };

    const int NK = KSs / 64;                 // 16 at SK=4
    stage(0);
    for (int kt = 0; kt < NK; ++kt) {
        __syncthreads();                     // drains vmcnt(0): tile staged
#pragma unroll
        for (int ks = 0; ks < 2; ++ks) {
            const unsigned short* rA = &As[ks][0] + rAo;
            const unsigned short* rB = &Bs[ks][0] + rBo;
            bf16x8 af[4], bfr[2];
#pragma unroll
            for (int mi = 0; mi < 4; ++mi) af[mi]  = *(const bf16x8*)(rA + mi * 16 * BK);
#pragma unroll
            for (int ni = 0; ni < 2; ++ni) bfr[ni] = *(const bf16x8*)(rB + ni * 16 * BK);
#pragma unroll
            for (int mi = 0; mi < 4; ++mi)
#pragma unroll
                for (int ni = 0; ni < 2; ++ni)
                    acc[mi][ni] = __builtin_amdgcn_mfma_f32_16x16x32_bf16(
                        af[mi], bfr[ni], acc[mi][ni], 0, 0, 0);
        }
        __syncthreads();                     // all waves done reading planes
        if (kt + 1 < NK) stage(kt + 1);      // safe: buffer free; completion
    }                                        // enforced by next first barrier

    // C/D layout: col = lanem, row = quad*4 + r; 16 lanes = one 64B segment.
    const int row0 = mt * BM + wm * 64 + quad * 4;
    const int col0 = nt * BN + wn * 32 + lanem;
    if (EPI == 0) {
        float bv[2];
#pragma unroll
        for (int ni = 0; ni < 2; ++ni) bv[ni] = (s == 0) ? bias[col0 + ni * 16] : 0.f;
        float* dst = (s == 0) ? out : parts + (size_t)(s - 1) * BATCH * OUT_F;
#pragma unroll
        for (int mi = 0; mi < 4; ++mi)
#pragma unroll
            for (int ni = 0; ni < 2; ++ni)
#pragma unroll
                for (int r = 0; r < 4; ++r)
                    dst[(size_t)(row0 + mi * 16 + r) * OUT_F + col0 + ni * 16] =
                        acc[mi][ni][r] + bv[ni];
    } else {
#pragma unroll
        for (int mi = 0; mi < 4; ++mi)
#pragma unroll
            for (int ni = 0; ni < 2; ++ni)
#pragma unroll
                for (int r = 0; r < 4; ++r)
                    atomicAdd(&out[(size_t)(row0 + mi * 16 + r) * OUT_F + col0 + ni * 16],
                              acc[mi][ni][r]);
    }
}

// ---------------------------------------------------------------------------
// K4: out += sum(parts[0..2])  (42 MB streamed, ~7 us). Separate kernel:
// the kernel boundary is ONE cheap system-scope flush -- R8 showed per-block
// device fences (buffer_wbl2 x1024) cost ~150 us. Do not re-fuse.
// ---------------------------------------------------------------------------
__global__ void reduce_parts(float* __restrict__ out,
                             const float* __restrict__ parts) {
    int i = blockIdx.x * 256 + threadIdx.x;          // 524288 float4s
    float4 a = ((const float4*)out)[i];
#pragma unroll
    for (int p = 0; p < 3; ++p) {
        float4 b = ((const float4*)(parts + (size_t)p * BATCH * OUT_F))[i];
        a.x += b.x; a.y += b.y; a.z += b.z; a.w += b.w;
    }
    ((float4*)out)[i] = a;
}

// ---------------------------------------------------------------------------
// ws: xb 4.19 | W 33.55 | parts 3 x 8.39 = 25.17  -> 62.9 MB (fallback if less)
// ---------------------------------------------------------------------------
extern "C" void kernel_launch(void* const* d_in, const int* in_sizes, int n_in,
                              void* d_out, int out_size, void* d_ws, size_t ws_size,
                              hipStream_t stream) {
    const float* x       = (const float*)d_in[0];
    const int*   row_idx = (const int*)d_in[1];
    const int*   col_idx = (const int*)d_in[2];
    const float* values  = (const float*)d_in[3];
    const float* bias    = (const float*)d_in[4];
    float*       out     = (float*)d_out;

    unsigned short* xb = (unsigned short*)d_ws;
    unsigned short* W  = xb + (size_t)BATCH * K_DIM;
    float* parts = (float*)(W + (size_t)OUT_F * K_DIM);
    size_t need = (size_t)BATCH * K_DIM * 2 + (size_t)OUT_F * K_DIM * 2
                + (size_t)3 * BATCH * OUT_F * 4;
    bool use_parts = (ws_size >= need);

    zero_w<<<ZW_BLOCKS, 256, 0, stream>>>((uint4*)W);

    int sc_blocks = NS_BLK + NC_BLK + (use_parts ? 0 : NB_BLK);
    scatcvt<<<sc_blocks, 256, 0, stream>>>(row_idx, col_idx, values, W,
                                           x, xb, bias, out);

    if (use_parts) {
        gemm_bt<0, 4><<<dim3(OUT_F / BN, BATCH / BM, 4), 512, 0, stream>>>(
            xb, W, bias, out, parts);
        reduce_parts<<<BATCH * OUT_F / 4 / 256, 256, 0, stream>>>(out, parts);
    } else {
        gemm_bt<1, 4><<<dim3(OUT_F / BN, BATCH / BM, 4), 512, 0, stream>>>(
            xb, W, bias, out, nullptr);
    }
}